// Round 9
// baseline (91.147 us; speedup 1.0000x reference)
//
#include <hip/hip_runtime.h>

#define N_  8
#define D_  64
#define H_  64
#define W_  64
#define HW_ (H_ * W_)
#define KK  25

// ---------------------------------------------------------------------------
// Kernel 1: per-block nonzero partial counts of cur and prev; also streams
// prev_mem (partials to pr, never consumed) to warm L3 for kernel 2.
// 512 blocks x 256 threads, 4096 elems/block, 64 blocks per batch. (Proven.)
// ---------------------------------------------------------------------------
__global__ __launch_bounds__(256) void count_nz_kernel(
    const float4* __restrict__ cur, const float4* __restrict__ prev,
    const float4* __restrict__ pmv,
    unsigned int* __restrict__ pc, unsigned int* __restrict__ pq,
    unsigned int* __restrict__ pr)
{
    __shared__ unsigned int sc[4], sp[4], sr[4];
    const int t    = threadIdx.x;
    const int wid  = t >> 6;
    const int lane = t & 63;

    unsigned int wc = 0, wp = 0, wr = 0;
#pragma unroll
    for (int j = 0; j < 4; ++j) {
        int idx = blockIdx.x * 1024 + j * 256 + t;
        float4 a = cur[idx];
        float4 b = prev[idx];
        float4 m = pmv[idx];
        wc += (unsigned)__popcll(__ballot(a.x != 0.f));
        wc += (unsigned)__popcll(__ballot(a.y != 0.f));
        wc += (unsigned)__popcll(__ballot(a.z != 0.f));
        wc += (unsigned)__popcll(__ballot(a.w != 0.f));
        wp += (unsigned)__popcll(__ballot(b.x != 0.f));
        wp += (unsigned)__popcll(__ballot(b.y != 0.f));
        wp += (unsigned)__popcll(__ballot(b.z != 0.f));
        wp += (unsigned)__popcll(__ballot(b.w != 0.f));
        wr += (unsigned)__popcll(__ballot(m.x != 0.f));
        wr += (unsigned)__popcll(__ballot(m.y != 0.f));
        wr += (unsigned)__popcll(__ballot(m.z != 0.f));
        wr += (unsigned)__popcll(__ballot(m.w != 0.f));
    }
    if (lane == 0) { sc[wid] = wc; sp[wid] = wp; sr[wid] = wr; }
    __syncthreads();
    if (t == 0) {
        pc[blockIdx.x] = sc[0] + sc[1] + sc[2] + sc[3];
        pq[blockIdx.x] = sp[0] + sp[1] + sp[2] + sp[3];
        pr[blockIdx.x] = sr[0] + sr[1] + sr[2] + sr[3];
    }
}

// ---------------------------------------------------------------------------
// Kernel 2: fused FeatureAlign = R6's proven phase structure, but 256-thread
// blocks so TWO independent blocks co-reside per CU (2 waves/SIMD, VGPR
// budget 256 -> no spill; LDS 25.6KB x2 = 51.2KB). Grid 512 = (n,y) with XCD
// swizzle n=b&7, y=b>>3 so same-n neighbor rows (window halo) share an XCD L2.
// Thread = 2 px x 8 ch: xp=tid&31, g=tid>>5 (ch-group, folded into per-lane
// 32-bit offsets). Phases: early prefetch (pm centers + counts) -> dot
// (contiguous float2 loads, free-flowing) -> LDS cross-group reduce ->
// weights (wave 0) -> output.
// ---------------------------------------------------------------------------
__global__ __launch_bounds__(256, 2) void feature_align_kernel(
    const float* __restrict__ cur, const float* __restrict__ prev,
    const float* __restrict__ pm, float* __restrict__ out,
    const unsigned int* __restrict__ pc, const unsigned int* __restrict__ pq)
{
    __shared__ float red[4][KK][64];    // 25.6 KB; aliased: red[0]=wght, red[1][0]=zflag

    const int b   = blockIdx.x;                  // 0..511
    const int n   = b & 7;                       // XCD swizzle: n fastest
    const int y   = b >> 3;                      // same-n y-neighbors 8 apart
    const int tid = threadIdx.x;
    const int xp  = tid & 31;                    // px-pair
    const int g   = tid >> 5;                    // ch-group 0..7 (8 ch each)
    const int x0  = xp * 2;

    // Per-lane d-invariant byte offsets; group channel base folded in.
    const unsigned goff = (unsigned)g * 8u * HW_ * 4u;   // < 1 MB, fits u32
    int cb[3];
#pragma unroll
    for (int i = 0; i < 3; ++i)
        cb[i] = min(max(x0 - 2 + 2 * i, 0), W_ - 2);     // even -> 8B aligned
    unsigned voff[5][3];
#pragma unroll
    for (int ky = 0; ky < 5; ++ky) {
        int qy = min(max(y + ky - 2, 0), H_ - 1);
#pragma unroll
        for (int i = 0; i < 3; ++i)
            voff[ky][i] = goff + (unsigned)((qy * W_ + cb[i]) * 4);
    }
    const unsigned curoff = goff + (unsigned)((y * W_ + x0) * 4);

    const size_t nbase = (size_t)n * D_ * HW_;
    const char* curb  = (const char*)(cur  + nbase);
    const char* prevb = (const char*)(prev + nbase);
    const char* pmb   = (const char*)(pm   + nbase);
    char*       outb  = (char*)(out + nbase);

    // ---- EARLY prefetch: pm centers (8 ch) + count partials ----
    float2 pmc[8];
#pragma unroll
    for (int dd = 0; dd < 8; ++dd)
        pmc[dd] = *(const float2*)(pmb + (size_t)dd * HW_ * 4 + curoff);
    unsigned int ccnt = 0, vcnt = 0;
    if (tid < 64) {
        ccnt = pc[(n << 6) + tid];
        vcnt = pq[(n << 6) + tid];
    }

    float acc0[KK], acc1[KK];
#pragma unroll
    for (int k = 0; k < KK; ++k) { acc0[k] = 0.f; acc1[k] = 0.f; }

    // ---- dot phase: 8 channels/thread, contiguous float2 loads ----
#pragma unroll
    for (int dd = 0; dd < 8; ++dd) {
        const char* cch = curb  + (size_t)dd * HW_ * 4;
        const char* pch = prevb + (size_t)dd * HW_ * 4;
        float2 c = *(const float2*)(cch + curoff);
        float2 t[5][3];
#pragma unroll
        for (int ky = 0; ky < 5; ++ky)
#pragma unroll
            for (int i = 0; i < 3; ++i)
                t[ky][i] = *(const float2*)(pch + voff[ky][i]);
#pragma unroll
        for (int ky = 0; ky < 5; ++ky) {
            float v[6] = { t[ky][0].x, t[ky][0].y, t[ky][1].x,
                           t[ky][1].y, t[ky][2].x, t[ky][2].y };
#pragma unroll
            for (int kx = 0; kx < 5; ++kx) {
                acc0[ky * 5 + kx] = fmaf(c.x, v[kx],     acc0[ky * 5 + kx]);
                acc1[ky * 5 + kx] = fmaf(c.y, v[kx + 1], acc1[ky * 5 + kx]);
            }
        }
    }

    // ---- cross-group reduction: waves 0,1 (g<4) write; waves 2,3 add ----
    if (g < 4) {
#pragma unroll
        for (int k = 0; k < KK; ++k)
            *(float2*)&red[g][k][x0] = make_float2(acc0[k], acc1[k]);
    }
    __syncthreads();
    if (g >= 4) {
#pragma unroll
        for (int k = 0; k < KK; ++k) {
            float2 t2 = *(float2*)&red[g - 4][k][x0];
            t2.x += acc0[k]; t2.y += acc1[k];
            *(float2*)&red[g - 4][k][x0] = t2;
        }
    }
    __syncthreads();

    // ---- weights: wave 0, one pixel per lane ----
    if (tid < 64) {
        const int px = tid;
        unsigned int cc = ccnt, vv = vcnt;
#pragma unroll
        for (int st = 32; st >= 1; st >>= 1) {
            cc += __shfl_xor(cc, st);
            vv += __shfl_xor(vv, st);
        }
        float scale = 1.0f / (((float)cc + 1e-8f) * ((float)vv + 1e-8f));

        float mass = 0.f;
        float cf[KK];
#pragma unroll
        for (int k = 0; k < KK; ++k) {
            float sm = red[0][k][px] + red[1][k][px]
                     + red[2][k][px] + red[3][k][px];
            int ky = k / 5, kx = k % 5;
            int py  = y + ky - 2;
            int pxc = px + kx - 2;
            bool val = (py >= 0) && (py < H_) && (pxc >= 0) && (pxc < W_);
            float c = val ? fmaxf(sm * scale, 0.f) : 0.f;
            cf[k] = c;
            mass += c;
        }
        bool  zero = fabsf(mass) < 1e-7f;
        float inv  = zero ? 0.f : 1.0f / mass;
        // Column px only touched by this lane -> alias-safe rewrite.
#pragma unroll
        for (int k = 0; k < KK; ++k) red[0][k][px] = cf[k] * inv;  // wght
        red[1][0][px] = zero ? 1.f : 0.f;                          // zflag
    }
    __syncthreads();

    // ---- output phase ----
    const float zf0 = red[1][0][x0];
    const float zf1 = red[1][0][x0 + 1];

    if (zf0 != 0.f && zf1 != 0.f) {
        // Hot path: pure stores of prefetched pm centers.
#pragma unroll
        for (int dd = 0; dd < 8; ++dd)
            *(float2*)(outb + (size_t)dd * HW_ * 4 + curoff) = pmc[dd];
    } else {
        // Cold path (correctness only on this data).
        float w0[KK], w1[KK];
#pragma unroll
        for (int k = 0; k < KK; ++k) {
            w0[k] = red[0][k][x0];
            w1[k] = red[0][k][x0 + 1];
        }
#pragma unroll
        for (int dd = 0; dd < 8; ++dd) {
            const char* pch = pmb + (size_t)dd * HW_ * 4;
            float2 t2[5][3];
#pragma unroll
            for (int ky = 0; ky < 5; ++ky)
#pragma unroll
                for (int i = 0; i < 3; ++i)
                    t2[ky][i] = *(const float2*)(pch + voff[ky][i]);
            float v0 = 0.f, v1 = 0.f;
#pragma unroll
            for (int ky = 0; ky < 5; ++ky) {
                float v[6] = { t2[ky][0].x, t2[ky][0].y, t2[ky][1].x,
                               t2[ky][1].y, t2[ky][2].x, t2[ky][2].y };
#pragma unroll
                for (int kx = 0; kx < 5; ++kx) {
                    v0 = fmaf(w0[ky * 5 + kx], v[kx],     v0);
                    v1 = fmaf(w1[ky * 5 + kx], v[kx + 1], v1);
                }
            }
            float2 o;
            o.x = (zf0 != 0.f) ? pmc[dd].x : v0;
            o.y = (zf1 != 0.f) ? pmc[dd].y : v1;
            *(float2*)(outb + (size_t)dd * HW_ * 4 + curoff) = o;
        }
    }
}

extern "C" void kernel_launch(void* const* d_in, const int* in_sizes, int n_in,
                              void* d_out, int out_size, void* d_ws, size_t ws_size,
                              hipStream_t stream)
{
    const float* cur  = (const float*)d_in[0];
    const float* prev = (const float*)d_in[1];
    const float* pm   = (const float*)d_in[2];
    float*       out  = (float*)d_out;
    unsigned int* pc  = (unsigned int*)d_ws;        // 512 partials (cur)
    unsigned int* pq  = pc + 512;                   // 512 partials (prev)
    unsigned int* pr  = pq + 512;                   // 512 partials (pm, unused)

    count_nz_kernel<<<512, 256, 0, stream>>>(
        (const float4*)cur, (const float4*)prev, (const float4*)pm, pc, pq, pr);

    feature_align_kernel<<<512, 256, 0, stream>>>(cur, prev, pm, out, pc, pq);
}